// Round 2
// baseline (1109.523 us; speedup 1.0000x reference)
//
#include <hip/hip_runtime.h>

typedef _Float16 h8 __attribute__((ext_vector_type(8)));
typedef _Float16 h4 __attribute__((ext_vector_type(4)));
typedef float f4 __attribute__((ext_vector_type(4)));
typedef float f16v __attribute__((ext_vector_type(16)));

#define MFMA16(a, b, c) __builtin_amdgcn_mfma_f32_16x16x32_f16((a), (b), (c), 0, 0, 0)
#define MFMA32(a, b, c) __builtin_amdgcn_mfma_f32_32x32x16_f16((a), (b), (c), 0, 0, 0)

// B=4, S=4096, D_IN=D_OUT=512

// ---------------- weight convert: Wt[z][n][k] = W_z[k][n] * (z==0 ? 0.5 : 1) ----------------
__global__ void wconv_kernel(const float* __restrict__ Wq, const float* __restrict__ Wk,
                             const float* __restrict__ Wv, _Float16* __restrict__ Wt) {
  int idx = blockIdx.x * 256 + threadIdx.x;
  int z = idx >> 15;
  int rem = idx & 32767;
  int n = rem >> 6;
  int k0 = (rem & 63) << 3;
  const float* W = (z == 0) ? Wq : (z == 1) ? Wk : Wv;
  float sc = (z == 0) ? 0.5f : 1.0f;
  h8 v;
#pragma unroll
  for (int j = 0; j < 8; ++j) v[j] = (_Float16)(W[(k0 + j) * 512 + n] * sc);
  *(h8*)&Wt[(size_t)z * 262144 + n * 512 + k0] = v;
}

// ---------------- QKV projection ----------------
// 128x128 tile, 4 waves, BK=64. Single reg-set staging; prefetch issued AFTER the
// stage barrier so HBM latency hides behind the MFMA phase. 3 blocks/CU.
__global__ __launch_bounds__(256, 3)
void proj_kernel(const float* __restrict__ x, const _Float16* __restrict__ Wt,
                 const float* __restrict__ bq, const float* __restrict__ bk,
                 const float* __restrict__ bv,
                 _Float16* __restrict__ Qh, _Float16* __restrict__ Kh, _Float16* __restrict__ Vt) {
  __shared__ _Float16 sA[128 * 72];
  __shared__ _Float16 sB[128 * 72];
  const int tid = threadIdx.x;
  const int wave = tid >> 6, lane = tid & 63;
  const int quad = lane >> 4, lr = lane & 15;
  const int mbase = blockIdx.x * 128;
  const int nbase = blockIdx.y * 128;
  const int z = blockIdx.z;
  const _Float16* W = Wt + (size_t)z * 262144;

  const int sr = tid >> 1;
  const int sseg = tid & 1;

  const int rbase = (wave & 1) * 64;
  const int cbase = (wave >> 1) * 64;

  float4 ax[8];
  int4 bx[4];

  f4 acc[4][4];
#pragma unroll
  for (int i = 0; i < 4; ++i)
#pragma unroll
    for (int j = 0; j < 4; ++j) {
      f4 zz = {0.f, 0.f, 0.f, 0.f};
      acc[i][j] = zz;
    }

  {  // preload kt = 0
    const float4* asrc = (const float4*)&x[(size_t)(mbase + sr) * 512 + sseg * 32];
#pragma unroll
    for (int i = 0; i < 8; ++i) ax[i] = asrc[i];
    const int4* bsrc = (const int4*)&W[(size_t)(nbase + sr) * 512 + sseg * 32];
#pragma unroll
    for (int i = 0; i < 4; ++i) bx[i] = bsrc[i];
  }

  for (int kt = 0; kt < 8; ++kt) {
    if (kt > 0) __syncthreads();
    // stage current chunk (fp32 -> fp16 convert for A)
#pragma unroll
    for (int i = 0; i < 4; ++i) {
      h8 v;
      float4 f0 = ax[2 * i], f1 = ax[2 * i + 1];
      v[0] = (_Float16)f0.x; v[1] = (_Float16)f0.y; v[2] = (_Float16)f0.z; v[3] = (_Float16)f0.w;
      v[4] = (_Float16)f1.x; v[5] = (_Float16)f1.y; v[6] = (_Float16)f1.z; v[7] = (_Float16)f1.w;
      *(h8*)&sA[sr * 72 + sseg * 32 + i * 8] = v;
    }
#pragma unroll
    for (int i = 0; i < 4; ++i) *(int4*)&sB[sr * 72 + sseg * 32 + i * 8] = bx[i];
    __syncthreads();
    if (kt + 1 < 8) {  // prefetch next chunk; drains at next iter's barrier (hidden by MFMA below)
      const float4* asrc = (const float4*)&x[(size_t)(mbase + sr) * 512 + (kt + 1) * 64 + sseg * 32];
#pragma unroll
      for (int i = 0; i < 8; ++i) ax[i] = asrc[i];
      const int4* bsrc = (const int4*)&W[(size_t)(nbase + sr) * 512 + (kt + 1) * 64 + sseg * 32];
#pragma unroll
      for (int i = 0; i < 4; ++i) bx[i] = bsrc[i];
    }
#pragma unroll
    for (int ks = 0; ks < 2; ++ks) {
      h8 a[4], bb[4];
#pragma unroll
      for (int rt = 0; rt < 4; ++rt)
        a[rt] = *(const h8*)&sA[(rbase + rt * 16 + lr) * 72 + ks * 32 + quad * 8];
#pragma unroll
      for (int ct = 0; ct < 4; ++ct)
        bb[ct] = *(const h8*)&sB[(cbase + ct * 16 + lr) * 72 + ks * 32 + quad * 8];
#pragma unroll
      for (int rt = 0; rt < 4; ++rt)
#pragma unroll
        for (int ct = 0; ct < 4; ++ct)
          acc[rt][ct] = MFMA16(a[rt], bb[ct], acc[rt][ct]);
    }
  }

  const float* bias = (z == 0) ? bq : (z == 1) ? bk : bv;
  const float bscale = (z == 0) ? 0.5f : 1.0f;
  _Float16* outQK = (z == 0) ? Qh : Kh;
#pragma unroll
  for (int ct = 0; ct < 4; ++ct) {
    const int col = nbase + cbase + ct * 16 + lr;
    const float bb = bias[col] * bscale;
#pragma unroll
    for (int rt = 0; rt < 4; ++rt) {
      const int row0 = mbase + rbase + rt * 16 + quad * 4;
      if (z == 2) {
        const int bidx = row0 >> 12, s = row0 & 4095;
        h4 v;
#pragma unroll
        for (int r = 0; r < 4; ++r) v[r] = (_Float16)(acc[rt][ct][r] + bb);
        *(h4*)&Vt[(size_t)bidx * 2097152 + (size_t)col * 4096 + s] = v;
      } else {
#pragma unroll
        for (int r = 0; r < 4; ++r)
          outQK[(size_t)(row0 + r) * 512 + col] = (_Float16)(acc[rt][ct][r] + bb);
      }
    }
  }
}

// ---------------- fused flash attention (restructured) ----------------
// 1 WG = 64 Q-rows, 8 waves (2 rowgrp x 4 colgrp), 32x32x16 MFMA, Q in regs (128 VGPR).
// KT=128 keys/step, two 64KB LDS buffers pipelined: K d-halves (QK) then V key-halves (PV).
// 7 barriers / 128 keys; staging loads issued a full phase before their drain barrier.
// XOR-swizzled unpadded LDS (slot = chunk ^ (row&7)) -> b128 bank floor.
__global__ __launch_bounds__(512, 2)
void attn_kernel(const _Float16* __restrict__ Qh, const _Float16* __restrict__ Kh,
                 const _Float16* __restrict__ Vt, float* __restrict__ out) {
  __shared__ _Float16 H0[32768];  // 64 KB
  __shared__ _Float16 H1[32768];  // 64 KB
  __shared__ _Float16 sP[64 * 136];
  __shared__ float sM[64], sL[64], sAl[64];
  __shared__ float sRedM[4][64], sRedS[4][64];

  const int tid = threadIdx.x;
  const int wave = tid >> 6, lane = tid & 63;
  const int l31 = lane & 31, l5 = lane >> 5;
  const int rg = wave >> 2, cg = wave & 3;

  const int w = blockIdx.x;             // XCD/batch swizzle: xcd = w&7 -> batch = (w>>1)&3
  const int b = (w >> 1) & 3;
  const int qt = ((w >> 3) << 1) | (w & 1);
  const int qbase = qt * 64;

  const char* KbB = (const char*)(Kh + ((size_t)b * 4096) * 512);
  const char* VbB = (const char*)(Vt + ((size_t)b * 512) * 4096);

  // staging maps
  const int s_key = tid >> 2, s_cs0 = (tid & 3) * 8;  // K-half: 128 keys x 32 chunks(16B)
  const int v_c = tid & 7, v_d0 = tid >> 3;           // V-half: 512 d x 8 chunks(16B)
  int4 st[4];

  auto issueK = [&](int kb, int ho, int bat) {
#pragma unroll
    for (int j = 0; j < 4; ++j) {
      int cs = s_cs0 + bat * 4 + j;
      st[j] = *(const int4*)(KbB + (size_t)(kb + s_key) * 1024 + ho * 512 + ((cs ^ (s_key & 7)) * 16));
    }
  };
  auto commitK = [&](_Float16* H, int bat) {
#pragma unroll
    for (int j = 0; j < 4; ++j) {
      int cs = s_cs0 + bat * 4 + j;
      *(int4*)&H[s_key * 256 + cs * 8] = st[j];
    }
  };
  auto issueV = [&](int kb, int kh, int bat) {
#pragma unroll
    for (int j = 0; j < 4; ++j) {
      int d = v_d0 + (bat * 4 + j) * 64;
      st[j] = *(const int4*)(VbB + (size_t)d * 8192 + (size_t)(kb + kh * 64) * 2 + ((v_c ^ (d & 7)) * 16));
    }
  };
  auto commitV = [&](_Float16* H, int bat) {
#pragma unroll
    for (int j = 0; j < 4; ++j) {
      int d = v_d0 + (bat * 4 + j) * 64;
      *(int4*)&H[d * 64 + v_c * 8] = st[j];
    }
  };

  // prologue: stage K-lo(step 0) into H0; init state
  issueK(0, 0, 0);
  if (tid < 64) { sM[tid] = -3.0e38f; sL[tid] = 0.f; }
  commitK(H0, 0);
  issueK(0, 0, 1);
  commitK(H0, 1);

  // Q fragments: A-layout row = lane&31 (+rg*32), k = kc*16 + l5*8 + j. 32 frags = 128 VGPR.
  h8 qf[32];
  {
    const _Float16* qp = Qh + ((size_t)(b * 4096 + qbase + rg * 32 + l31)) * 512 + l5 * 8;
#pragma unroll
    for (int kc = 0; kc < 32; ++kc) qf[kc] = *(const h8*)(qp + kc * 16);
  }

  f16v O[4];
#pragma unroll
  for (int ct = 0; ct < 4; ++ct)
#pragma unroll
    for (int i = 0; i < 16; ++i) O[ct][i] = 0.f;

  __syncthreads();

  const int keyl = cg * 32 + l31;  // QK B-frag key row in LDS
  const int kx = keyl & 7;

  for (int step = 0; step < 32; ++step) {
    const int kb = step << 7;

    f16v S;
#pragma unroll
    for (int i = 0; i < 16; ++i) S[i] = 0.f;

    // ---- P1: QK-lo from H0; stage K-hi -> H1 ----
    issueK(kb, 1, 0);
#pragma unroll
    for (int kc = 0; kc < 8; ++kc) {
      h8 bf = *(const h8*)&H0[keyl * 256 + (((kc * 2 + l5) ^ kx)) * 8];
      S = MFMA32(qf[kc], bf, S);
    }
    commitK(H1, 0);
    issueK(kb, 1, 1);
#pragma unroll
    for (int kc = 8; kc < 16; ++kc) {
      h8 bf = *(const h8*)&H0[keyl * 256 + (((kc * 2 + l5) ^ kx)) * 8];
      S = MFMA32(qf[kc], bf, S);
    }
    commitK(H1, 1);
    __syncthreads();

    // ---- P2: QK-hi from H1; stage V-lo -> H0 ----
    issueV(kb, 0, 0);
#pragma unroll
    for (int kc = 0; kc < 8; ++kc) {
      h8 bf = *(const h8*)&H1[keyl * 256 + (((kc * 2 + l5) ^ kx)) * 8];
      S = MFMA32(qf[16 + kc], bf, S);
    }
    commitV(H0, 0);
    issueV(kb, 0, 1);
#pragma unroll
    for (int kc = 8; kc < 16; ++kc) {
      h8 bf = *(const h8*)&H1[keyl * 256 + (((kc * 2 + l5) ^ kx)) * 8];
      S = MFMA32(qf[16 + kc], bf, S);
    }
    commitV(H0, 1);
    __syncthreads();

    // ---- P3a: per-wave row-max over 32 cols (in-reg); stage V-hi -> H1 (issue+bat0) ----
    issueV(kb, 1, 0);
    float m[16];
#pragma unroll
    for (int i = 0; i < 16; ++i) m[i] = S[i];
#pragma unroll
    for (int i = 0; i < 16; ++i) {
      m[i] = fmaxf(m[i], __shfl_xor(m[i], 1));
      m[i] = fmaxf(m[i], __shfl_xor(m[i], 2));
      m[i] = fmaxf(m[i], __shfl_xor(m[i], 4));
      m[i] = fmaxf(m[i], __shfl_xor(m[i], 8));
      m[i] = fmaxf(m[i], __shfl_xor(m[i], 16));
    }
    commitV(H1, 0);
    issueV(kb, 1, 1);
#pragma unroll
    for (int r = 0; r < 16; ++r)
      if (l31 == r) sRedM[cg][rg * 32 + (r & 3) + 8 * (r >> 2) + 4 * l5] = m[r];
    __syncthreads();

    // ---- P3b: combine max (threads 0..63) ----
    if (tid < 64) {
      float mo = sM[tid];
      float mn = fmaxf(fmaxf(fmaxf(sRedM[0][tid], sRedM[1][tid]),
                             fmaxf(sRedM[2][tid], sRedM[3][tid])), mo);
      sAl[tid] = __expf(mo - mn);
      sM[tid] = mn;
    }
    __syncthreads();

    // ---- P3c: exp in regs, write P (fp16), row-sum reduce, O rescale; commit V-hi bat1 ----
    commitV(H1, 1);
    float4 mq[4];
#pragma unroll
    for (int q2 = 0; q2 < 4; ++q2) mq[q2] = *(const float4*)&sM[rg * 32 + q2 * 8 + l5 * 4];
    float p[16];
#pragma unroll
    for (int i = 0; i < 16; ++i) {
      float mm = (i & 1) ? ((i & 2) ? ((i >> 2) == 0 ? mq[0].w : (i >> 2) == 1 ? mq[1].w : (i >> 2) == 2 ? mq[2].w : mq[3].w)
                                    : ((i >> 2) == 0 ? mq[0].y : (i >> 2) == 1 ? mq[1].y : (i >> 2) == 2 ? mq[2].y : mq[3].y))
                         : ((i & 2) ? ((i >> 2) == 0 ? mq[0].z : (i >> 2) == 1 ? mq[1].z : (i >> 2) == 2 ? mq[2].z : mq[3].z)
                                    : ((i >> 2) == 0 ? mq[0].x : (i >> 2) == 1 ? mq[1].x : (i >> 2) == 2 ? mq[2].x : mq[3].x));
      p[i] = __expf(S[i] - mm);
    }
#pragma unroll
    for (int i = 0; i < 16; ++i)
      sP[(rg * 32 + (i & 3) + 8 * (i >> 2) + 4 * l5) * 136 + cg * 32 + l31] = (_Float16)p[i];
    float s[16];
#pragma unroll
    for (int i = 0; i < 16; ++i) s[i] = p[i];
#pragma unroll
    for (int i = 0; i < 16; ++i) {
      s[i] += __shfl_xor(s[i], 1);
      s[i] += __shfl_xor(s[i], 2);
      s[i] += __shfl_xor(s[i], 4);
      s[i] += __shfl_xor(s[i], 8);
      s[i] += __shfl_xor(s[i], 16);
    }
#pragma unroll
    for (int r = 0; r < 16; ++r)
      if (l31 == r) sRedS[cg][rg * 32 + (r & 3) + 8 * (r >> 2) + 4 * l5] = s[r];
    // O rescale by alpha
    {
      float4 aq[4];
#pragma unroll
      for (int q2 = 0; q2 < 4; ++q2) aq[q2] = *(const float4*)&sAl[rg * 32 + q2 * 8 + l5 * 4];
#pragma unroll
      for (int ct = 0; ct < 4; ++ct)
#pragma unroll
        for (int i = 0; i < 16; ++i) {
          float aa = (i & 1) ? ((i & 2) ? aq[i >> 2].w : aq[i >> 2].y)
                             : ((i & 2) ? aq[i >> 2].z : aq[i >> 2].x);
          O[ct][i] *= aa;
        }
    }
    __syncthreads();

    // ---- P4: sL update (threads<64); PV-lo from H0 (keys kb..kb+63) ----
    if (tid < 64) {
      float s4 = sRedS[0][tid] + sRedS[1][tid] + sRedS[2][tid] + sRedS[3][tid];
      sL[tid] = sL[tid] * sAl[tid] + s4;
    }
    {
      h8 pf[4];
#pragma unroll
      for (int kc = 0; kc < 4; ++kc)
        pf[kc] = *(const h8*)&sP[(rg * 32 + l31) * 136 + kc * 16 + l5 * 8];
#pragma unroll
      for (int kc = 0; kc < 4; ++kc) {
#pragma unroll
        for (int ct = 0; ct < 4; ++ct) {
          int d = cg * 128 + ct * 32 + l31;
          h8 vf = *(const h8*)&H0[d * 64 + (((kc * 2 + l5) ^ (d & 7))) * 8];
          O[ct] = MFMA32(pf[kc], vf, O[ct]);
        }
      }
    }
    __syncthreads();

    // ---- P5: PV-hi from H1 (keys kb+64..kb+127); stage K-lo(step+1) -> H0 ----
    {
      const int nkb = kb + 128;
      const bool more = (step + 1 < 32);
      if (more) issueK(nkb, 0, 0);
      h8 pf[4];
#pragma unroll
      for (int kc = 0; kc < 4; ++kc)
        pf[kc] = *(const h8*)&sP[(rg * 32 + l31) * 136 + 64 + kc * 16 + l5 * 8];
#pragma unroll
      for (int kc = 0; kc < 2; ++kc) {
#pragma unroll
        for (int ct = 0; ct < 4; ++ct) {
          int d = cg * 128 + ct * 32 + l31;
          h8 vf = *(const h8*)&H1[d * 64 + (((kc * 2 + l5) ^ (d & 7))) * 8];
          O[ct] = MFMA32(pf[kc], vf, O[ct]);
        }
      }
      if (more) { commitK(H0, 0); issueK(nkb, 0, 1); }
#pragma unroll
      for (int kc = 2; kc < 4; ++kc) {
#pragma unroll
        for (int ct = 0; ct < 4; ++ct) {
          int d = cg * 128 + ct * 32 + l31;
          h8 vf = *(const h8*)&H1[d * 64 + (((kc * 2 + l5) ^ (d & 7))) * 8];
          O[ct] = MFMA32(pf[kc], vf, O[ct]);
        }
      }
      if (more) commitK(H0, 1);
    }
    __syncthreads();
  }

  // ---- epilogue: O / l ----
  float4 lq[4];
#pragma unroll
  for (int q2 = 0; q2 < 4; ++q2) lq[q2] = *(const float4*)&sL[rg * 32 + q2 * 8 + l5 * 4];
#pragma unroll
  for (int ct = 0; ct < 4; ++ct) {
    const int col = cg * 128 + ct * 32 + l31;
#pragma unroll
    for (int i = 0; i < 16; ++i) {
      float ll = (i & 1) ? ((i & 2) ? lq[i >> 2].w : lq[i >> 2].y)
                         : ((i & 2) ? lq[i >> 2].z : lq[i >> 2].x);
      const int row = qbase + rg * 32 + (i & 3) + 8 * (i >> 2) + 4 * l5;
      out[((size_t)b * 4096 + row) * 512 + col] = O[ct][i] * (1.0f / ll);
    }
  }
}

extern "C" void kernel_launch(void* const* d_in, const int* in_sizes, int n_in,
                              void* d_out, int out_size, void* d_ws, size_t ws_size,
                              hipStream_t stream) {
  (void)in_sizes; (void)n_in; (void)out_size; (void)ws_size;
  const float* x  = (const float*)d_in[0];
  const float* Wq = (const float*)d_in[1];
  const float* bq = (const float*)d_in[2];
  const float* Wk = (const float*)d_in[3];
  const float* bk = (const float*)d_in[4];
  const float* Wv = (const float*)d_in[5];
  const float* bv = (const float*)d_in[6];
  float* out = (float*)d_out;
  char* ws = (char*)d_ws;
  _Float16* Qh = (_Float16*)(ws);
  _Float16* Kh = (_Float16*)(ws + ((size_t)1 << 24));
  _Float16* Vt = (_Float16*)(ws + ((size_t)2 << 24));
  _Float16* Wt = (_Float16*)(ws + ((size_t)3 << 24));

  wconv_kernel<<<dim3(384), dim3(256), 0, stream>>>(Wq, Wk, Wv, Wt);
  proj_kernel<<<dim3(128, 4, 3), dim3(256), 0, stream>>>(x, Wt, bq, bk, bv, Qh, Kh, Vt);
  attn_kernel<<<dim3(256), dim3(512), 0, stream>>>(Qh, Kh, Vt, out);
}

// Round 3
// 858.108 us; speedup vs baseline: 1.2930x; 1.2930x over previous
//
#include <hip/hip_runtime.h>

typedef _Float16 h8 __attribute__((ext_vector_type(8)));
typedef float f4 __attribute__((ext_vector_type(4)));
typedef float f16v __attribute__((ext_vector_type(16)));

#define MFMA16(a, b, c) __builtin_amdgcn_mfma_f32_16x16x32_f16((a), (b), (c), 0, 0, 0)
#define MFMA32(a, b, c) __builtin_amdgcn_mfma_f32_32x32x16_f16((a), (b), (c), 0, 0, 0)

// async global->LDS, 16B per lane; LDS dest = wave-uniform base + lane*16
__device__ static inline void gl_lds16(const void* g, void* l) {
  __builtin_amdgcn_global_load_lds((const __attribute__((address_space(1))) unsigned int*)g,
                                   (__attribute__((address_space(3))) unsigned int*)l, 16, 0, 0);
}

// B=4, S=4096, D_IN=D_OUT=512
//
// Workspace image layouts (swizzle baked into GLOBAL so linear global_load_lds
// staging yields bank-conflict-floor ds_read_b128 fragment reads):
//  Qimg: per (b, qt[0..127]) 32KB block: addr = c*512B + r32*16B, c = d>>3 (0..63), r32 = s&31
//  Kimg: per (b, step[0..15], dq[0..3]) 64KB block: addr = key*256B + ((c ^ (key&15))*16B),
//        key = s&255, c = (d&127)>>3 (0..15)
//  Vimg: per (b, step[0..15], kq[0..3]) 64KB block: addr = d*128B + ((c ^ (d&7))*16B),
//        c = (s&63)>>3 (0..7)

// ---------------- weight convert: Wt[z][n][k] = W_z[k][n] * (z==0 ? 0.5 : 1) ----------------
__global__ void wconv_kernel(const float* __restrict__ Wq, const float* __restrict__ Wk,
                             const float* __restrict__ Wv, _Float16* __restrict__ Wt) {
  int idx = blockIdx.x * 256 + threadIdx.x;
  int z = idx >> 15;
  int rem = idx & 32767;
  int n = rem >> 6;
  int k0 = (rem & 63) << 3;
  const float* W = (z == 0) ? Wq : (z == 1) ? Wk : Wv;
  float sc = (z == 0) ? 0.5f : 1.0f;
  h8 v;
#pragma unroll
  for (int j = 0; j < 8; ++j) v[j] = (_Float16)(W[(k0 + j) * 512 + n] * sc);
  *(h8*)&Wt[(size_t)z * 262144 + n * 512 + k0] = v;
}

// ---------------- QKV projection -> swizzled images ----------------
__global__ __launch_bounds__(256, 2)
void proj_kernel(const float* __restrict__ x, const _Float16* __restrict__ Wt,
                 const float* __restrict__ bq, const float* __restrict__ bk,
                 const float* __restrict__ bv,
                 char* __restrict__ Qimg, char* __restrict__ Kimg, char* __restrict__ Vimg) {
  __shared__ _Float16 sMem[18432];  // sA|sB for main loop; reused as sC (128x136) in epilogue
  _Float16* sA = sMem;
  _Float16* sB = sMem + 9216;
  const int tid = threadIdx.x;
  const int wave = tid >> 6, lane = tid & 63;
  const int quad = lane >> 4, lr = lane & 15;
  const int mbase = blockIdx.x * 128;
  const int nbase = blockIdx.y * 128;
  const int z = blockIdx.z;
  const _Float16* W = Wt + (size_t)z * 262144;

  const int sr = tid >> 1;
  const int sseg = tid & 1;
  const int rbase = (wave & 1) * 64;
  const int cbase = (wave >> 1) * 64;

  float4 ax[8];
  int4 bx[4];

  f4 acc[4][4];
#pragma unroll
  for (int i = 0; i < 4; ++i)
#pragma unroll
    for (int j = 0; j < 4; ++j) {
      f4 zz = {0.f, 0.f, 0.f, 0.f};
      acc[i][j] = zz;
    }

  {  // preload kt = 0
    const float4* asrc = (const float4*)&x[(size_t)(mbase + sr) * 512 + sseg * 32];
#pragma unroll
    for (int i = 0; i < 8; ++i) ax[i] = asrc[i];
    const int4* bsrc = (const int4*)&W[(size_t)(nbase + sr) * 512 + sseg * 32];
#pragma unroll
    for (int i = 0; i < 4; ++i) bx[i] = bsrc[i];
  }

  for (int kt = 0; kt < 8; ++kt) {
    if (kt > 0) __syncthreads();
#pragma unroll
    for (int i = 0; i < 4; ++i) {
      h8 v;
      float4 f0 = ax[2 * i], f1 = ax[2 * i + 1];
      v[0] = (_Float16)f0.x; v[1] = (_Float16)f0.y; v[2] = (_Float16)f0.z; v[3] = (_Float16)f0.w;
      v[4] = (_Float16)f1.x; v[5] = (_Float16)f1.y; v[6] = (_Float16)f1.z; v[7] = (_Float16)f1.w;
      *(h8*)&sA[sr * 72 + sseg * 32 + i * 8] = v;
    }
#pragma unroll
    for (int i = 0; i < 4; ++i) *(int4*)&sB[sr * 72 + sseg * 32 + i * 8] = bx[i];
    __syncthreads();
    if (kt + 1 < 8) {
      const float4* asrc = (const float4*)&x[(size_t)(mbase + sr) * 512 + (kt + 1) * 64 + sseg * 32];
#pragma unroll
      for (int i = 0; i < 8; ++i) ax[i] = asrc[i];
      const int4* bsrc = (const int4*)&W[(size_t)(nbase + sr) * 512 + (kt + 1) * 64 + sseg * 32];
#pragma unroll
      for (int i = 0; i < 4; ++i) bx[i] = bsrc[i];
    }
#pragma unroll
    for (int ks = 0; ks < 2; ++ks) {
      h8 a[4], bb[4];
#pragma unroll
      for (int rt = 0; rt < 4; ++rt)
        a[rt] = *(const h8*)&sA[(rbase + rt * 16 + lr) * 72 + ks * 32 + quad * 8];
#pragma unroll
      for (int ct = 0; ct < 4; ++ct)
        bb[ct] = *(const h8*)&sB[(cbase + ct * 16 + lr) * 72 + ks * 32 + quad * 8];
#pragma unroll
      for (int rt = 0; rt < 4; ++rt)
#pragma unroll
        for (int ct = 0; ct < 4; ++ct)
          acc[rt][ct] = MFMA16(a[rt], bb[ct], acc[rt][ct]);
    }
  }

  // ---- epilogue: stash fp16 C-tile in LDS, then vectorized stores to images ----
  const float* bias = (z == 0) ? bq : (z == 1) ? bk : bv;
  const float bscale = (z == 0) ? 0.5f : 1.0f;
  _Float16* sC = sMem;  // 128 x 136
  __syncthreads();      // sA/sB reads done
#pragma unroll
  for (int ct = 0; ct < 4; ++ct) {
    const int coll = cbase + ct * 16 + lr;
    const float bb = bias[nbase + coll] * bscale;
#pragma unroll
    for (int rt = 0; rt < 4; ++rt) {
      const int rowl = rbase + rt * 16 + quad * 4;
      if (z == 2) {  // transposed stash: sC[d_local][s_local]
#pragma unroll
        for (int r = 0; r < 4; ++r)
          sC[coll * 136 + rowl + r] = (_Float16)(acc[rt][ct][r] + bb);
      } else {       // row-major stash: sC[s_local][d_local]
#pragma unroll
        for (int r = 0; r < 4; ++r)
          sC[(rowl + r) * 136 + coll] = (_Float16)(acc[rt][ct][r] + bb);
      }
    }
  }
  __syncthreads();

  const int trow = tid >> 1, thalf = tid & 1;
  if (z == 0) {
    const int s = mbase + trow;
    const int b_ = s >> 12, qt = (s & 4095) >> 5, r32 = s & 31;
    char* blk = Qimg + (size_t)(b_ * 128 + qt) * 32768;
#pragma unroll
    for (int k = 0; k < 8; ++k) {
      const int c = thalf * 8 + k;            // local d-chunk 0..15
      const int cglob = (nbase >> 3) + c;     // global d-chunk 0..63
      *(int4*)(blk + cglob * 512 + r32 * 16) = *(const int4*)&sC[trow * 136 + c * 8];
    }
  } else if (z == 1) {
    const int s = mbase + trow;
    const int b_ = s >> 12, s4 = s & 4095;
    const int step = s4 >> 8, keyk = s4 & 255, dq = nbase >> 7;
    char* blk = Kimg + (size_t)(((b_ * 16 + step) * 4) + dq) * 65536;
#pragma unroll
    for (int k = 0; k < 8; ++k) {
      const int c = thalf * 8 + k;            // d-chunk within quarter 0..15
      *(int4*)(blk + keyk * 256 + ((c ^ (keyk & 15)) * 16)) = *(const int4*)&sC[trow * 136 + c * 8];
    }
  } else {
    const int d = nbase + trow;
#pragma unroll
    for (int k = 0; k < 8; ++k) {
      const int s_local = thalf * 64 + k * 8;
      const int s = mbase + s_local;
      const int b_ = s >> 12, s4 = s & 4095;
      const int step = s4 >> 8, kq = (s4 >> 6) & 3, cj = (s4 & 63) >> 3;
      char* blk = Vimg + (size_t)(((b_ * 16 + step) * 4) + kq) * 65536;
      *(int4*)(blk + d * 128 + ((cj ^ (d & 7)) * 16)) = *(const int4*)&sC[trow * 136 + s_local];
    }
  }
}

// ---------------- fused flash attention ----------------
// WG = 32 Q-rows, 8 waves (1 rowgroup x 8 colgroups), 32x32x16 MFMA, KT=256 keys/step.
// Q in regs (qf[32]=128 VGPR), O = 32 fp32/lane, S = 16 -> no spill at 256-cap.
// Tiles per step: [K dq0..3, V kq0..3], dbuf H0/H1 64KB, pattern:
//   { compute(buf t&1); barrier; stage(t+2 -> freed buf) }  => loads fly a full phase.
// K/V LDS reads have zero cross-wave duplication (disjoint key/d slices per wave).
__global__ __launch_bounds__(512, 2)
void attn_kernel(const char* __restrict__ Qimg, const char* __restrict__ Kimg,
                 const char* __restrict__ Vimg, float* __restrict__ out) {
  __shared__ _Float16 H0[32768];  // 64KB
  __shared__ _Float16 H1[32768];  // 64KB
  __shared__ _Float16 sP[8192];   // 32 rows x 256 keys, XOR-16 swizzled
  __shared__ float sRedM[8][32];
  __shared__ float sRedS[8][32];
  __shared__ float sM[32], sL[32], sAl[32];

  const int tid = threadIdx.x;
  const int wave = tid >> 6, lane = tid & 63;
  const int l31 = lane & 31, l5 = lane >> 5;
  const int cg = wave;  // key-col group (QK) / d group (PV)

  const int w = blockIdx.x;                 // XCD swizzle: xcd=w&7 -> batch=(w&7)>>1
  const int b = (w & 7) >> 1;
  const int qt = ((w >> 3) << 1) | (w & 1); // 0..127

  const char* Kbase = Kimg + (size_t)b * (16 * 4 * 65536);
  const char* Vbase = Vimg + (size_t)b * (16 * 4 * 65536);

  auto tileSrc = [&](int t) -> const char* {
    const int ph = t & 7;
    const char* base = (ph < 4) ? Kbase : Vbase;
    return base + (size_t)((t >> 3) * 4 + (ph & 3)) * 65536;
  };
  auto stage = [&](int t) {
    const char* src = tileSrc(t);
    char* dst = (char*)((t & 1) ? H1 : H0);
#pragma unroll
    for (int j = 0; j < 8; ++j) {
      const int off = (j * 8 + wave) * 1024 + lane * 16;
      gl_lds16(src + off, dst + off);
    }
  };

  // prologue: stage K0->H0, K1->H1; load Q frags; init state
  stage(0);
  stage(1);
  if (tid < 32) { sM[tid] = -3.0e38f; sL[tid] = 0.f; }

  h8 qf[32];  // A-frags: row = l31, k = kc*16 + l5*8 + j
  {
    const char* Qblk = Qimg + (size_t)(b * 128 + qt) * 32768;
#pragma unroll
    for (int kc = 0; kc < 32; ++kc)
      qf[kc] = *(const h8*)(Qblk + (kc * 2 + l5) * 512 + l31 * 16);
  }

  f16v O0, O1;
#pragma unroll
  for (int i = 0; i < 16; ++i) { O0[i] = 0.f; O1[i] = 0.f; }

  const int key = cg * 32 + l31;
  const int keyOff = key * 128, kx = key & 15;
  const int d0 = cg * 64 + l31, d1 = d0 + 32;
  const int pRow = l31 * 256, px = l31 & 15;

  __syncthreads();  // drain T0, T1

  for (int step = 0; step < 16; ++step) {
    f16v S;
#pragma unroll
    for (int i = 0; i < 16; ++i) S[i] = 0.f;

    // ---- QK: 4 d-quarters ----
#pragma unroll
    for (int q = 0; q < 4; ++q) {
      const _Float16* H = (q & 1) ? H1 : H0;
#pragma unroll
      for (int kcl = 0; kcl < 8; ++kcl) {
        h8 bf = *(const h8*)&H[keyOff + ((((kcl << 1) | l5) ^ kx) << 3)];
        S = MFMA32(qf[q * 8 + kcl], bf, S);
      }
      __syncthreads();
      stage(step * 8 + q + 2);  // K2,K3,V0,V1 -> the buffer just freed
    }

    // ---- softmax (online, over this step's 256 keys) ----
    float m[16];
#pragma unroll
    for (int i = 0; i < 16; ++i) m[i] = S[i];
#pragma unroll
    for (int i = 0; i < 16; ++i) {
      m[i] = fmaxf(m[i], __shfl_xor(m[i], 1));
      m[i] = fmaxf(m[i], __shfl_xor(m[i], 2));
      m[i] = fmaxf(m[i], __shfl_xor(m[i], 4));
      m[i] = fmaxf(m[i], __shfl_xor(m[i], 8));
      m[i] = fmaxf(m[i], __shfl_xor(m[i], 16));
    }
#pragma unroll
    for (int i = 0; i < 16; ++i)
      if (l31 == i) sRedM[cg][(i & 3) + 8 * (i >> 2) + 4 * l5] = m[i];
    __syncthreads();  // S-bar1 (also drains V1)

    if (tid < 32) {
      const float mo = sM[tid];
      float mn = mo;
#pragma unroll
      for (int g = 0; g < 8; ++g) mn = fmaxf(mn, sRedM[g][tid]);
      sAl[tid] = __expf(mo - mn);
      sM[tid] = mn;
    }
    __syncthreads();  // S-bar2

    {
      f4 mq[4];
#pragma unroll
      for (int g2 = 0; g2 < 4; ++g2) mq[g2] = *(const f4*)&sM[g2 * 8 + l5 * 4];
#pragma unroll
      for (int i = 0; i < 16; ++i) S[i] = __expf(S[i] - mq[i >> 2][i & 3]);
      // P -> LDS (fp16, swizzled); row = C-layout row, col = this wave's keys
      const int ck = key >> 3, ke = key & 7;
#pragma unroll
      for (int i = 0; i < 16; ++i) {
        const int row = (i & 3) + 8 * (i >> 2) + 4 * l5;
        sP[row * 256 + ((ck ^ (row & 15)) << 3) + ke] = (_Float16)S[i];
      }
      // row sums (destroys S)
#pragma unroll
      for (int i = 0; i < 16; ++i) {
        S[i] += __shfl_xor(S[i], 1);
        S[i] += __shfl_xor(S[i], 2);
        S[i] += __shfl_xor(S[i], 4);
        S[i] += __shfl_xor(S[i], 8);
        S[i] += __shfl_xor(S[i], 16);
      }
#pragma unroll
      for (int i = 0; i < 16; ++i)
        if (l31 == i) sRedS[cg][(i & 3) + 8 * (i >> 2) + 4 * l5] = S[i];
      // O rescale by alpha
      f4 aq[4];
#pragma unroll
      for (int g2 = 0; g2 < 4; ++g2) aq[g2] = *(const f4*)&sAl[g2 * 8 + l5 * 4];
#pragma unroll
      for (int i = 0; i < 16; ++i) {
        const float a = aq[i >> 2][i & 3];
        O0[i] *= a;
        O1[i] *= a;
      }
    }
    __syncthreads();  // S-bar3: P visible; V0 long drained

    // ---- PV: 4 key-quarters ----
#pragma unroll
    for (int kq = 0; kq < 4; ++kq) {
      const _Float16* H = (kq & 1) ? H1 : H0;
      if (kq == 0 && tid < 32) {
        float s8 = sRedS[0][tid] + sRedS[1][tid] + sRedS[2][tid] + sRedS[3][tid] +
                   sRedS[4][tid] + sRedS[5][tid] + sRedS[6][tid] + sRedS[7][tid];
        sL[tid] = sL[tid] * sAl[tid] + s8;
      }
      h8 pf[4];
#pragma unroll
      for (int kc = 0; kc < 4; ++kc) {
        const int c = kq * 8 + kc * 2 + l5;
        pf[kc] = *(const h8*)&sP[pRow + ((c ^ px) << 3)];
      }
#pragma unroll
      for (int kc = 0; kc < 4; ++kc) {
        const int cc = (kc << 1) | l5;
        h8 vf0 = *(const h8*)&H[d0 * 64 + ((cc ^ (d0 & 7)) << 3)];
        O0 = MFMA32(pf[kc], vf0, O0);
        h8 vf1 = *(const h8*)&H[d1 * 64 + ((cc ^ (d1 & 7)) << 3)];
        O1 = MFMA32(pf[kc], vf1, O1);
      }
      __syncthreads();
      const int t2 = step * 8 + 4 + kq + 2;  // V2,V3, next K0,K1
      if (t2 < 128) stage(t2);
    }
  }

  // ---- epilogue: O / l ----
  f4 lq[4];
#pragma unroll
  for (int g2 = 0; g2 < 4; ++g2) lq[g2] = *(const f4*)&sL[g2 * 8 + l5 * 4];
#pragma unroll
  for (int i = 0; i < 16; ++i) {
    const float inv = 1.0f / lq[i >> 2][i & 3];
    const int row = qt * 32 + (i & 3) + 8 * (i >> 2) + 4 * l5;
    float* op = &out[((size_t)b * 4096 + row) * 512];
    op[d0] = O0[i] * inv;
    op[d1] = O1[i] * inv;
  }
}

extern "C" void kernel_launch(void* const* d_in, const int* in_sizes, int n_in,
                              void* d_out, int out_size, void* d_ws, size_t ws_size,
                              hipStream_t stream) {
  (void)in_sizes; (void)n_in; (void)out_size; (void)ws_size;
  const float* x  = (const float*)d_in[0];
  const float* Wq = (const float*)d_in[1];
  const float* bq = (const float*)d_in[2];
  const float* Wk = (const float*)d_in[3];
  const float* bk = (const float*)d_in[4];
  const float* Wv = (const float*)d_in[5];
  const float* bv = (const float*)d_in[6];
  float* out = (float*)d_out;
  char* ws = (char*)d_ws;
  // ws: Qimg [0,16M), Kimg [16M,32M), Vimg [32M,48M), Wt [48M,49.5M)
  char* Qimg = ws;
  char* Kimg = ws + ((size_t)16 << 20);
  char* Vimg = ws + ((size_t)32 << 20);
  _Float16* Wt = (_Float16*)(ws + ((size_t)48 << 20));

  wconv_kernel<<<dim3(384), dim3(256), 0, stream>>>(Wq, Wk, Wv, Wt);
  proj_kernel<<<dim3(128, 4, 3), dim3(256), 0, stream>>>(x, Wt, bq, bk, bv, Qimg, Kimg, Vimg);
  attn_kernel<<<dim3(512), dim3(512), 0, stream>>>(Qimg, Kimg, Vimg, out);
}